// Round 3
// baseline (771.778 us; speedup 1.0000x reference)
//
#include <hip/hip_runtime.h>

typedef __attribute__((ext_vector_type(4))) float f32x4;
typedef __attribute__((ext_vector_type(8))) short bf16x8;
typedef unsigned int uint;
typedef unsigned short ushort;

// ---------- helpers ----------

__device__ __forceinline__ ushort f2bf(float f) {
  union { float f; uint u; } v; v.f = f;
  uint u = v.u;
  uint r = (u + 0x7FFFu + ((u >> 16) & 1u)) >> 16;  // RNE
  return (ushort)r;
}
__device__ __forceinline__ float to_f32(float f) { return f; }
__device__ __forceinline__ float to_f32(ushort u) {
  union { uint u; float f; } v; v.u = ((uint)u) << 16;
  return v.f;
}

// packed f32x2 -> bf16x2 (RNE), 1 instruction
__device__ __forceinline__ uint cvt_pk_bf16(float lo, float hi) {
  uint r;
  asm("v_cvt_pk_bf16_f32 %0, %1, %2" : "=v"(r) : "v"(lo), "v"(hi));
  return r;
}

__device__ __forceinline__ void gload_lds16(const void* g, void* l) {
  __builtin_amdgcn_global_load_lds(
      (const __attribute__((address_space(1))) void*)g,
      (__attribute__((address_space(3))) void*)l, 16, 0, 0);
}

// ---------- pre-pass kernels ----------

__global__ __launch_bounds__(256)
void conv_bf16(const float* __restrict__ in, ushort* __restrict__ out, long n) {
  long i = ((long)blockIdx.x * 256 + threadIdx.x) * 8;
  if (i >= n) return;
  float4 a = *(const float4*)(in + i);
  float4 b = *(const float4*)(in + i + 4);
  union { ushort u[8]; uint4 v; } o;
  o.u[0] = f2bf(a.x); o.u[1] = f2bf(a.y); o.u[2] = f2bf(a.z); o.u[3] = f2bf(a.w);
  o.u[4] = f2bf(b.x); o.u[5] = f2bf(b.y); o.u[6] = f2bf(b.z); o.u[7] = f2bf(b.w);
  *(uint4*)(out + i) = o.v;
}

template<typename T>
__global__ __launch_bounds__(256)
void transpose_to_bf16(const T* __restrict__ in, ushort* __restrict__ out, int R, int C) {
  __shared__ float tile[32][33];
  const size_t boff = (size_t)blockIdx.z * R * C;
  in += boff; out += boff;
  const int r0 = blockIdx.y * 32, c0 = blockIdx.x * 32;
  const int x = threadIdx.x, y = threadIdx.y;
#pragma unroll
  for (int j = 0; j < 32; j += 8)
    tile[y + j][x] = to_f32(in[(size_t)(r0 + y + j) * C + c0 + x]);
  __syncthreads();
#pragma unroll
  for (int j = 0; j < 32; j += 8)
    out[(size_t)(c0 + y + j) * R + r0 + x] = f2bf(tile[x][y + j]);
}

__global__ __launch_bounds__(256)
void pack_mask(const int* __restrict__ in, uint* __restrict__ out) {
  long t = (long)blockIdx.x * 256 + threadIdx.x;
  const int4* p = (const int4*)(in + t * 32);
  uint w = 0;
#pragma unroll
  for (int i = 0; i < 8; ++i) {
    int4 v = p[i];
    w |= (v.x > 0 ? 1u : 0u) << (i * 4 + 0);
    w |= (v.y > 0 ? 1u : 0u) << (i * 4 + 1);
    w |= (v.z > 0 ? 1u : 0u) << (i * 4 + 2);
    w |= (v.w > 0 ? 1u : 0u) << (i * 4 + 3);
  }
  out[t] = w;
}

// ---------- GEMM: C[M][N] = A[M][K] * Bt[N][K]^T  (m97 structure, unchanged) ----

template<int OUT_BF16>
__global__ __launch_bounds__(256)
void gemm_bt(const ushort* __restrict__ A, const ushort* __restrict__ Bt,
             void* __restrict__ C, int M, int N, int K, float scale) {
  __shared__ ushort lA[128 * 64];
  __shared__ ushort lB[128 * 64];
  const int tid = threadIdx.x;
  const int wid = tid >> 6;
  const int lane = tid & 63;
  const int lg = lane >> 4, li = lane & 15;
  const int m0 = blockIdx.y * 128;
  const int n0 = blockIdx.x * 128;
  const int wr = (wid >> 1) * 64;
  const int wc = (wid & 1) * 64;

  f32x4 acc[4][4] = {};
  const char* Ab = (const char*)A;
  const char* Bb = (const char*)Bt;

  for (int kt = 0; kt < K; kt += 64) {
    __syncthreads();
#pragma unroll
    for (int i = 0; i < 4; ++i) {
      int flat = i * 4096 + tid * 16;
      int row = flat >> 7;
      int colb = flat & 127;
      gload_lds16(Ab + ((size_t)(m0 + row) * K + kt) * 2 + colb,
                  (char*)lA + i * 4096 + wid * 1024);
    }
#pragma unroll
    for (int i = 0; i < 4; ++i) {
      int flat = i * 4096 + tid * 16;
      int row = flat >> 7;
      int colb = flat & 127;
      gload_lds16(Bb + ((size_t)(n0 + row) * K + kt) * 2 + colb,
                  (char*)lB + i * 4096 + wid * 1024);
    }
    __syncthreads();
#pragma unroll
    for (int ks = 0; ks < 2; ++ks) {
      bf16x8 af[4], bfr[4];
#pragma unroll
      for (int m = 0; m < 4; ++m)
        af[m] = *(const bf16x8*)&lA[(wr + m * 16 + li) * 64 + ks * 32 + lg * 8];
#pragma unroll
      for (int n = 0; n < 4; ++n)
        bfr[n] = *(const bf16x8*)&lB[(wc + n * 16 + li) * 64 + ks * 32 + lg * 8];
#pragma unroll
      for (int m = 0; m < 4; ++m)
#pragma unroll
        for (int n = 0; n < 4; ++n)
          acc[m][n] = __builtin_amdgcn_mfma_f32_16x16x32_bf16(af[m], bfr[n], acc[m][n], 0, 0, 0);
    }
  }

  const int r0 = m0 + wr + lg * 4;
  const int c0 = n0 + wc + li;
#pragma unroll
  for (int m = 0; m < 4; ++m)
#pragma unroll
    for (int n = 0; n < 4; ++n)
#pragma unroll
      for (int r = 0; r < 4; ++r) {
        size_t idx = (size_t)(r0 + m * 16 + r) * N + (c0 + n * 16);
        float v = acc[m][n][r] * scale;
        if (OUT_BF16) ((ushort*)C)[idx] = f2bf(v);
        else          ((float*)C)[idx]  = v;
      }
}

// ---------- flash attention v3 ----------
// QW=2 register blocking: 4 waves x 32 q = 128 q per block, KV tile 64.
// Each ak read feeds 2 MFMAs; av fragments cached in registers across both
// q-groups. K tile swizzled with (row&15)<<4 (full 16-slot spread, 256-B rows).
// 2-phase dbuf pipeline, one barrier per KV iteration. P goes through a shared
// per-wave 2KB lP, serialized across q-groups (in-order per-wave DS pipe).

__global__ __launch_bounds__(256)
void flash_attn3(const ushort* __restrict__ Q, const ushort* __restrict__ K,
                 const ushort* __restrict__ VT, const uint* __restrict__ maskp,
                 ushort* __restrict__ X) {
  __shared__ ushort lK[2][64 * 128];   // [kv][hd], 256-B rows, swz (row&15)<<4
  __shared__ ushort lVT[2][128 * 64];  // [hd][kv], 128-B rows, swz (row&7)<<4
  __shared__ ushort lP[4][16 * 64];    // per-wave P^T [q][k], swz (q&7)<<4

  const int tid = threadIdx.x;
  const int wid = tid >> 6;
  const int lane = tid & 63;
  const int lg = lane >> 4, li = lane & 15;

  // XCD-clustered: 1024 blocks; 8 bh per XCD, 16 q-tiles each
  const int flat = blockIdx.x;
  const int xcd = flat & 7;
  const int j = flat >> 3;            // 0..127
  const int bh = xcd * 8 + (j >> 4);
  const int qt = j & 15;
  const int b = bh >> 4, h = bh & 15;
  const int q0 = qt * 128;
  const int qbase = q0 + wid * 32;    // wave's 32 q-rows

  // Q as MFMA B-operand, 2 groups of 16 q
  bf16x8 bq[2][4];
#pragma unroll
  for (int g = 0; g < 2; ++g) {
    const ushort* qrow = Q + (size_t)(b * 2048 + qbase + g * 16 + li) * 2048 + h * 128;
#pragma unroll
    for (int kk = 0; kk < 4; ++kk)
      bq[g][kk] = *(const bf16x8*)(qrow + kk * 32 + lg * 8);
  }

  const uint* mqb[2] = {
      maskp + (size_t)(b * 2048 + qbase + li) * 64,
      maskp + (size_t)(b * 2048 + qbase + 16 + li) * 64};
  uint2 wc[2] = {*(const uint2*)mqb[0], *(const uint2*)mqb[1]};

  f32x4 acc_o[2][8] = {};  // O^T[hd = f*16 + lg*4 + r][q = li], per group
  float m[2] = {-3e38f, -3e38f}, l[2] = {0.f, 0.f};

  // staging source pointers (advance by constant stride per tile)
  const char* gk[4];
  const char* gv[4];
#pragma unroll
  for (int i = 0; i < 4; ++i) {
    int fl = i * 4096 + tid * 16;
    int rowK = fl >> 8;
    int colK = (fl & 255) ^ ((rowK & 15) << 4);
    gk[i] = (const char*)K + ((size_t)(b * 2048 + rowK) * 2048 + h * 128) * 2 + colK;
    int rowV = fl >> 7;
    int colV = (fl & 127) ^ ((rowV & 7) << 4);
    gv[i] = (const char*)VT + ((size_t)((b * 16 + h) * 128 + rowV) * 2048) * 2 + colV;
  }

  // prologue: stage tile 0
#pragma unroll
  for (int i = 0; i < 4; ++i)
    gload_lds16(gk[i], (char*)lK[0] + i * 4096 + wid * 1024);
#pragma unroll
  for (int i = 0; i < 4; ++i)
    gload_lds16(gv[i], (char*)lVT[0] + i * 4096 + wid * 1024);
#pragma unroll
  for (int i = 0; i < 4; ++i) { gk[i] += 262144; gv[i] += 128; }
  __syncthreads();

  ushort* lp = lP[wid];

  for (int it = 0; it < 32; ++it) {
    const int cur = it & 1;
    uint2 wn[2];
    if (it < 31) {
      // issue next tile's loads first — latency hides under compute
#pragma unroll
      for (int i = 0; i < 4; ++i)
        gload_lds16(gk[i], (char*)lK[cur ^ 1] + i * 4096 + wid * 1024);
#pragma unroll
      for (int i = 0; i < 4; ++i)
        gload_lds16(gv[i], (char*)lVT[cur ^ 1] + i * 4096 + wid * 1024);
#pragma unroll
      for (int i = 0; i < 4; ++i) { gk[i] += 262144; gv[i] += 128; }
      wn[0] = *(const uint2*)(mqb[0] + (it + 1) * 2);
      wn[1] = *(const uint2*)(mqb[1] + (it + 1) * 2);
    }
    const char* lk = (const char*)lK[cur];
    const char* lv = (const char*)lVT[cur];

    // QK^T swapped: A = K-strip, B = Q cols; each ak feeds both q-groups
    f32x4 accs[2][4] = {};
#pragma unroll
    for (int kk = 0; kk < 4; ++kk)
#pragma unroll
      for (int n = 0; n < 4; ++n) {
        bf16x8 ak = *(const bf16x8*)(lk + (n * 16 + li) * 256 +
                                     ((kk * 64 + lg * 16) ^ (li << 4)));
        accs[0][n] = __builtin_amdgcn_mfma_f32_16x16x32_bf16(ak, bq[0][kk], accs[0][n], 0, 0, 0);
        accs[1][n] = __builtin_amdgcn_mfma_f32_16x16x32_bf16(ak, bq[1][kk], accs[1][n], 0, 0, 0);
      }

    bf16x8 av[2][8];  // V^T fragments cached across q-groups
#pragma unroll
    for (int g = 0; g < 2; ++g) {
      // mask + lane-local softmax (16 k-values per lane, one q per lane)
      float sv[16];
      float pmax = -3e38f;
#pragma unroll
      for (int n = 0; n < 4; ++n) {
        uint w = (n < 2) ? wc[g].x : wc[g].y;
#pragma unroll
        for (int r = 0; r < 4; ++r) {
          int bit = (n & 1) * 16 + lg * 4 + r;
          float s = ((w >> bit) & 1u) ? accs[g][n][r] : -1e10f;
          sv[n * 4 + r] = s;
          pmax = fmaxf(pmax, s);
        }
      }
      pmax = fmaxf(pmax, __shfl_xor(pmax, 16, 64));
      pmax = fmaxf(pmax, __shfl_xor(pmax, 32, 64));

      // defer-max (T13)
      if (!__all(pmax - m[g] <= 8.0f)) {
        float mnew = fmaxf(m[g], pmax);
        float alpha = __expf(m[g] - mnew);
        l[g] *= alpha;
#pragma unroll
        for (int f = 0; f < 8; ++f)
#pragma unroll
          for (int r = 0; r < 4; ++r) acc_o[g][f][r] *= alpha;
        m[g] = mnew;
      }

      float sum = 0.f;
      uint pk[8];
#pragma unroll
      for (int i = 0; i < 8; ++i) {
        float p0 = __expf(sv[2 * i] - m[g]);      // bounded by e^8
        float p1 = __expf(sv[2 * i + 1] - m[g]);
        sum += p0 + p1;
        pk[i] = cvt_pk_bf16(p0, p1);
      }
      sum += __shfl_xor(sum, 16, 64);
      sum += __shfl_xor(sum, 32, 64);
      l[g] += sum;

      // P^T -> per-wave LDS [q=li][k]; lane writes k = n*16+lg*4+{0..3}
#pragma unroll
      for (int n = 0; n < 4; ++n) {
        uint2 pw; pw.x = pk[2 * n]; pw.y = pk[2 * n + 1];
        *(uint2*)((char*)lp + li * 128 + ((n * 32 + lg * 8) ^ ((li & 7) << 4))) = pw;
      }
      // in-order per-wave DS pipe: write->read (RAW) and read->write (WAR across
      // groups) are both safe without a barrier.

      // PV swapped: A = V^T strip (cached for g=0, reused for g=1), B = P^T cols
#pragma unroll
      for (int kc = 0; kc < 2; ++kc) {
        bf16x8 bp = *(const bf16x8*)((const char*)lp + li * 128 +
                                     ((kc * 64 + lg * 16) ^ ((li & 7) << 4)));
#pragma unroll
        for (int f = 0; f < 8; ++f) {
          if (g == 0)
            av[kc][f] = *(const bf16x8*)(lv + (f * 16 + li) * 128 +
                                         ((kc * 64 + lg * 16) ^ ((li & 7) << 4)));
          acc_o[g][f] = __builtin_amdgcn_mfma_f32_16x16x32_bf16(av[kc][f], bp, acc_o[g][f], 0, 0, 0);
        }
      }
    }

    if (it < 31) { wc[0] = wn[0]; wc[1] = wn[1]; }
    __syncthreads();  // next buffer staged+visible; this buffer free to overwrite
  }

  // epilogue: O[q][hd], hd = f*16 + lg*4 + r; 8B packed stores
#pragma unroll
  for (int g = 0; g < 2; ++g) {
    const float inv_l = 1.0f / l[g];
    ushort* xrow = X + (size_t)(b * 2048 + qbase + g * 16 + li) * 2048 + h * 128;
#pragma unroll
    for (int f = 0; f < 8; ++f) {
      union { ushort u[4]; uint2 v; } o;
#pragma unroll
      for (int r = 0; r < 4; ++r) o.u[r] = f2bf(acc_o[g][f][r] * inv_l);
      *(uint2*)(xrow + f * 16 + lg * 4) = o.v;
    }
  }
}

// ---------- launch ----------

extern "C" void kernel_launch(void* const* d_in, const int* in_sizes, int n_in,
                              void* d_out, int out_size, void* d_ws, size_t ws_size,
                              hipStream_t stream) {
  const float* inputs_q  = (const float*)d_in[0];
  const float* inputs_kv = (const float*)d_in[1];
  const int*   mask      = (const int*)d_in[2];
  const float* Wq        = (const float*)d_in[3];
  const float* Wk        = (const float*)d_in[4];
  const float* Wv        = (const float*)d_in[5];
  const float* Wo        = (const float*)d_in[6];
  float* out = (float*)d_out;
  char* ws = (char*)d_ws;

  uint*   maskp = (uint*)(ws + 0);                 //   2,097,152
  ushort* xq    = (ushort*)(ws + 2097152);         //  33,554,432 (reused as VT)
  ushort* xkv   = (ushort*)(ws + 35651584);        //  33,554,432 (reused as X)
  ushort* WqT   = (ushort*)(ws + 69206016);        //   8,388,608
  ushort* WkT   = (ushort*)(ws + 77594624);
  ushort* WvT   = (ushort*)(ws + 85983232);
  ushort* WoT   = (ushort*)(ws + 94371840);
  ushort* Qb    = (ushort*)(ws + 102760448);       //  33,554,432
  ushort* Kb    = (ushort*)(ws + 136314880);
  ushort* Vb    = (ushort*)(ws + 169869312);
  ushort* VTb   = xq;   // V^T, written after xq dead
  ushort* Xb    = xkv;  // attention output, written after xkv dead

  const long NE = 8192L * 2048;
  conv_bf16<<<8192, 256, 0, stream>>>(inputs_q,  xq,  NE);
  conv_bf16<<<8192, 256, 0, stream>>>(inputs_kv, xkv, NE);

  dim3 tb(32, 8);
  transpose_to_bf16<float><<<dim3(64, 64, 1), tb, 0, stream>>>(Wq, WqT, 2048, 2048);
  transpose_to_bf16<float><<<dim3(64, 64, 1), tb, 0, stream>>>(Wk, WkT, 2048, 2048);
  transpose_to_bf16<float><<<dim3(64, 64, 1), tb, 0, stream>>>(Wv, WvT, 2048, 2048);
  transpose_to_bf16<float><<<dim3(64, 64, 1), tb, 0, stream>>>(Wo, WoT, 2048, 2048);

  pack_mask<<<2048, 256, 0, stream>>>(mask, maskp);

  const float qscale = 0.08838834764831845f;  // 1/sqrt(128)
  gemm_bt<1><<<dim3(16, 64), 256, 0, stream>>>(xq,  WqT, Qb, 8192, 2048, 2048, qscale);
  gemm_bt<1><<<dim3(16, 64), 256, 0, stream>>>(xkv, WkT, Kb, 8192, 2048, 2048, 1.0f);
  gemm_bt<1><<<dim3(16, 64), 256, 0, stream>>>(xkv, WvT, Vb, 8192, 2048, 2048, 1.0f);

  transpose_to_bf16<ushort><<<dim3(64, 64, 4), tb, 0, stream>>>(Vb, VTb, 2048, 2048);

  flash_attn3<<<1024, 256, 0, stream>>>(Qb, Kb, VTb, maskp, Xb);

  gemm_bt<0><<<dim3(16, 64), 256, 0, stream>>>(Xb, WoT, out, 8192, 2048, 2048, 1.0f);
}

// Round 4
// 678.786 us; speedup vs baseline: 1.1370x; 1.1370x over previous
//
#include <hip/hip_runtime.h>

typedef __attribute__((ext_vector_type(4))) float f32x4;
typedef __attribute__((ext_vector_type(8))) short bf16x8;
typedef unsigned int uint;
typedef unsigned short ushort;

// ---------- helpers ----------

__device__ __forceinline__ ushort f2bf(float f) {
  union { float f; uint u; } v; v.f = f;
  uint u = v.u;
  uint r = (u + 0x7FFFu + ((u >> 16) & 1u)) >> 16;  // RNE
  return (ushort)r;
}
__device__ __forceinline__ float to_f32(float f) { return f; }
__device__ __forceinline__ float to_f32(ushort u) {
  union { uint u; float f; } v; v.u = ((uint)u) << 16;
  return v.f;
}

// packed f32x2 -> bf16x2 (RNE), 1 instruction
__device__ __forceinline__ uint cvt_pk_bf16(float lo, float hi) {
  uint r;
  asm("v_cvt_pk_bf16_f32 %0, %1, %2" : "=v"(r) : "v"(lo), "v"(hi));
  return r;
}

__device__ __forceinline__ void gload_lds16(const void* g, void* l) {
  __builtin_amdgcn_global_load_lds(
      (const __attribute__((address_space(1))) void*)g,
      (__attribute__((address_space(3))) void*)l, 16, 0, 0);
}

// ---------- pre-pass kernels ----------

__global__ __launch_bounds__(256)
void conv_bf16(const float* __restrict__ in, ushort* __restrict__ out, long n) {
  long i = ((long)blockIdx.x * 256 + threadIdx.x) * 8;
  if (i >= n) return;
  float4 a = *(const float4*)(in + i);
  float4 b = *(const float4*)(in + i + 4);
  union { ushort u[8]; uint4 v; } o;
  o.u[0] = f2bf(a.x); o.u[1] = f2bf(a.y); o.u[2] = f2bf(a.z); o.u[3] = f2bf(a.w);
  o.u[4] = f2bf(b.x); o.u[5] = f2bf(b.y); o.u[6] = f2bf(b.z); o.u[7] = f2bf(b.w);
  *(uint4*)(out + i) = o.v;
}

template<typename T>
__global__ __launch_bounds__(256)
void transpose_to_bf16(const T* __restrict__ in, ushort* __restrict__ out, int R, int C) {
  __shared__ float tile[32][33];
  const size_t boff = (size_t)blockIdx.z * R * C;
  in += boff; out += boff;
  const int r0 = blockIdx.y * 32, c0 = blockIdx.x * 32;
  const int x = threadIdx.x, y = threadIdx.y;
#pragma unroll
  for (int j = 0; j < 32; j += 8)
    tile[y + j][x] = to_f32(in[(size_t)(r0 + y + j) * C + c0 + x]);
  __syncthreads();
#pragma unroll
  for (int j = 0; j < 32; j += 8)
    out[(size_t)(c0 + y + j) * R + r0 + x] = f2bf(tile[x][y + j]);
}

__global__ __launch_bounds__(256)
void pack_mask(const int* __restrict__ in, uint* __restrict__ out) {
  long t = (long)blockIdx.x * 256 + threadIdx.x;
  const int4* p = (const int4*)(in + t * 32);
  uint w = 0;
#pragma unroll
  for (int i = 0; i < 8; ++i) {
    int4 v = p[i];
    w |= (v.x > 0 ? 1u : 0u) << (i * 4 + 0);
    w |= (v.y > 0 ? 1u : 0u) << (i * 4 + 1);
    w |= (v.z > 0 ? 1u : 0u) << (i * 4 + 2);
    w |= (v.w > 0 ? 1u : 0u) << (i * 4 + 3);
  }
  out[t] = w;
}

// ---------- GEMM: C[M][N] = A[M][K] * Bt[N][K]^T  (m97 structure) ----------
// + bijective XCD-clustered block swizzle (T1): each XCD gets 8 m-panels x all
// 16 n-panels -> A-panel L2-private per XCD. Requires grid = 16 x 64 = 1024.

template<int OUT_BF16>
__global__ __launch_bounds__(256)
void gemm_bt(const ushort* __restrict__ A, const ushort* __restrict__ Bt,
             void* __restrict__ C, int M, int N, int K, float scale) {
  __shared__ ushort lA[128 * 64];
  __shared__ ushort lB[128 * 64];
  const int tid = threadIdx.x;
  const int wid = tid >> 6;
  const int lane = tid & 63;
  const int lg = lane >> 4, li = lane & 15;

  // XCD swizzle: flat dispatch id -> xcd = flat&7; give each XCD a contiguous
  // chunk of the (m,n) space, n fastest.
  const int flat = blockIdx.y * gridDim.x + blockIdx.x;
  const int per = (gridDim.x * gridDim.y) >> 3;  // blocks per XCD
  const int w = (flat & 7) * per + (flat >> 3);
  const int m0 = (w / gridDim.x) * 128;
  const int n0 = (w % gridDim.x) * 128;

  const int wr = (wid >> 1) * 64;
  const int wc = (wid & 1) * 64;

  f32x4 acc[4][4] = {};
  const char* Ab = (const char*)A;
  const char* Bb = (const char*)Bt;

  for (int kt = 0; kt < K; kt += 64) {
    __syncthreads();
#pragma unroll
    for (int i = 0; i < 4; ++i) {
      int fl = i * 4096 + tid * 16;
      int row = fl >> 7;
      int colb = fl & 127;
      gload_lds16(Ab + ((size_t)(m0 + row) * K + kt) * 2 + colb,
                  (char*)lA + i * 4096 + wid * 1024);
    }
#pragma unroll
    for (int i = 0; i < 4; ++i) {
      int fl = i * 4096 + tid * 16;
      int row = fl >> 7;
      int colb = fl & 127;
      gload_lds16(Bb + ((size_t)(n0 + row) * K + kt) * 2 + colb,
                  (char*)lB + i * 4096 + wid * 1024);
    }
    __syncthreads();
#pragma unroll
    for (int ks = 0; ks < 2; ++ks) {
      bf16x8 af[4], bfr[4];
#pragma unroll
      for (int m = 0; m < 4; ++m)
        af[m] = *(const bf16x8*)&lA[(wr + m * 16 + li) * 64 + ks * 32 + lg * 8];
#pragma unroll
      for (int n = 0; n < 4; ++n)
        bfr[n] = *(const bf16x8*)&lB[(wc + n * 16 + li) * 64 + ks * 32 + lg * 8];
#pragma unroll
      for (int m = 0; m < 4; ++m)
#pragma unroll
        for (int n = 0; n < 4; ++n)
          acc[m][n] = __builtin_amdgcn_mfma_f32_16x16x32_bf16(af[m], bfr[n], acc[m][n], 0, 0, 0);
    }
  }

  const int r0 = m0 + wr + lg * 4;
  const int c0 = n0 + wc + li;
#pragma unroll
  for (int m = 0; m < 4; ++m)
#pragma unroll
    for (int n = 0; n < 4; ++n)
#pragma unroll
      for (int r = 0; r < 4; ++r) {
        size_t idx = (size_t)(r0 + m * 16 + r) * N + (c0 + n * 16);
        float v = acc[m][n][r] * scale;
        if (OUT_BF16) ((ushort*)C)[idx] = f2bf(v);
        else          ((float*)C)[idx]  = v;
      }
}

// ---------- flash attention v4 ----------
// QW=2 (128 q/block) with occupancy restored to 2 blocks/CU: V^T fragments are
// no longer register-cached; instead P for BOTH q-groups is staged in LDS and
// PV runs one fused pass (av read once per iter, transient). LDS = 80 KB
// (2 blocks = 160 KB exactly). __launch_bounds__(256,2) caps regs at 256 total.

__global__ __launch_bounds__(256, 2)
void flash_attn4(const ushort* __restrict__ Q, const ushort* __restrict__ K,
                 const ushort* __restrict__ VT, const uint* __restrict__ maskp,
                 ushort* __restrict__ X) {
  __shared__ ushort lK[2][64 * 128];    // [kv][hd], 256-B rows, swz (row&15)<<4
  __shared__ ushort lVT[2][128 * 64];   // [hd][kv], 128-B rows, swz (row&7)<<4
  __shared__ ushort lP[4][2][16 * 64];  // per-wave, per-group P^T [q][k]

  const int tid = threadIdx.x;
  const int wid = tid >> 6;
  const int lane = tid & 63;
  const int lg = lane >> 4, li = lane & 15;

  // XCD-clustered: 1024 blocks; 8 bh per XCD, 16 q-tiles each
  const int flat = blockIdx.x;
  const int xcd = flat & 7;
  const int j = flat >> 3;            // 0..127
  const int bh = xcd * 8 + (j >> 4);
  const int qt = j & 15;
  const int b = bh >> 4, h = bh & 15;
  const int q0 = qt * 128;
  const int qbase = q0 + wid * 32;    // wave's 32 q-rows

  // Q as MFMA B-operand, 2 groups of 16 q
  bf16x8 bq[2][4];
#pragma unroll
  for (int g = 0; g < 2; ++g) {
    const ushort* qrow = Q + (size_t)(b * 2048 + qbase + g * 16 + li) * 2048 + h * 128;
#pragma unroll
    for (int kk = 0; kk < 4; ++kk)
      bq[g][kk] = *(const bf16x8*)(qrow + kk * 32 + lg * 8);
  }

  const uint* mqb[2] = {
      maskp + (size_t)(b * 2048 + qbase + li) * 64,
      maskp + (size_t)(b * 2048 + qbase + 16 + li) * 64};
  uint2 wcur[2] = {*(const uint2*)mqb[0], *(const uint2*)mqb[1]};

  f32x4 acc_o[2][8] = {};  // O^T[hd = f*16 + lg*4 + r][q = li], per group
  float m[2] = {-3e38f, -3e38f}, l[2] = {0.f, 0.f};

  // staging source pointers (advance by constant stride per tile)
  const char* gk[4];
  const char* gv[4];
#pragma unroll
  for (int i = 0; i < 4; ++i) {
    int fl = i * 4096 + tid * 16;
    int rowK = fl >> 8;
    int colK = (fl & 255) ^ ((rowK & 15) << 4);
    gk[i] = (const char*)K + ((size_t)(b * 2048 + rowK) * 2048 + h * 128) * 2 + colK;
    int rowV = fl >> 7;
    int colV = (fl & 127) ^ ((rowV & 7) << 4);
    gv[i] = (const char*)VT + ((size_t)((b * 16 + h) * 128 + rowV) * 2048) * 2 + colV;
  }

  // prologue: stage tile 0
#pragma unroll
  for (int i = 0; i < 4; ++i)
    gload_lds16(gk[i], (char*)lK[0] + i * 4096 + wid * 1024);
#pragma unroll
  for (int i = 0; i < 4; ++i)
    gload_lds16(gv[i], (char*)lVT[0] + i * 4096 + wid * 1024);
#pragma unroll
  for (int i = 0; i < 4; ++i) { gk[i] += 262144; gv[i] += 128; }
  __syncthreads();

  ushort* lp0 = lP[wid][0];
  ushort* lp1 = lP[wid][1];

  for (int it = 0; it < 32; ++it) {
    const int cur = it & 1;
    uint2 wn[2];
    if (it < 31) {
      // issue next tile's loads first — latency hides under compute
#pragma unroll
      for (int i = 0; i < 4; ++i)
        gload_lds16(gk[i], (char*)lK[cur ^ 1] + i * 4096 + wid * 1024);
#pragma unroll
      for (int i = 0; i < 4; ++i)
        gload_lds16(gv[i], (char*)lVT[cur ^ 1] + i * 4096 + wid * 1024);
#pragma unroll
      for (int i = 0; i < 4; ++i) { gk[i] += 262144; gv[i] += 128; }
      wn[0] = *(const uint2*)(mqb[0] + (it + 1) * 2);
      wn[1] = *(const uint2*)(mqb[1] + (it + 1) * 2);
    }
    const char* lk = (const char*)lK[cur];
    const char* lv = (const char*)lVT[cur];

    // QK^T swapped: A = K-strip, B = Q cols; each ak feeds both q-groups
    f32x4 accs[2][4] = {};
#pragma unroll
    for (int kk = 0; kk < 4; ++kk)
#pragma unroll
      for (int n = 0; n < 4; ++n) {
        bf16x8 ak = *(const bf16x8*)(lk + (n * 16 + li) * 256 +
                                     ((kk * 64 + lg * 16) ^ (li << 4)));
        accs[0][n] = __builtin_amdgcn_mfma_f32_16x16x32_bf16(ak, bq[0][kk], accs[0][n], 0, 0, 0);
        accs[1][n] = __builtin_amdgcn_mfma_f32_16x16x32_bf16(ak, bq[1][kk], accs[1][n], 0, 0, 0);
      }

    // mask + lane-local softmax per group; P -> lP[wid][g]
#pragma unroll
    for (int g = 0; g < 2; ++g) {
      float sv[16];
      float pmax = -3e38f;
#pragma unroll
      for (int n = 0; n < 4; ++n) {
        uint w = (n < 2) ? wcur[g].x : wcur[g].y;
#pragma unroll
        for (int r = 0; r < 4; ++r) {
          int bit = (n & 1) * 16 + lg * 4 + r;
          float s = ((w >> bit) & 1u) ? accs[g][n][r] : -1e10f;
          sv[n * 4 + r] = s;
          pmax = fmaxf(pmax, s);
        }
      }
      pmax = fmaxf(pmax, __shfl_xor(pmax, 16, 64));
      pmax = fmaxf(pmax, __shfl_xor(pmax, 32, 64));

      // defer-max (T13)
      if (!__all(pmax - m[g] <= 8.0f)) {
        float mnew = fmaxf(m[g], pmax);
        float alpha = __expf(m[g] - mnew);
        l[g] *= alpha;
#pragma unroll
        for (int f = 0; f < 8; ++f)
#pragma unroll
          for (int r = 0; r < 4; ++r) acc_o[g][f][r] *= alpha;
        m[g] = mnew;
      }

      float sum = 0.f;
      uint pk[8];
#pragma unroll
      for (int i = 0; i < 8; ++i) {
        float p0 = __expf(sv[2 * i] - m[g]);      // bounded by e^8
        float p1 = __expf(sv[2 * i + 1] - m[g]);
        sum += p0 + p1;
        pk[i] = cvt_pk_bf16(p0, p1);
      }
      sum += __shfl_xor(sum, 16, 64);
      sum += __shfl_xor(sum, 32, 64);
      l[g] += sum;

      ushort* lpg = g ? lp1 : lp0;
#pragma unroll
      for (int n = 0; n < 4; ++n) {
        uint2 pw; pw.x = pk[2 * n]; pw.y = pk[2 * n + 1];
        *(uint2*)((char*)lpg + li * 128 + ((n * 32 + lg * 8) ^ ((li & 7) << 4))) = pw;
      }
    }
    // in-order per-wave DS pipe: ds_write -> ds_read RAW is safe w/o barrier

    // PV fused over both groups: av read ONCE per (kc,f), transient
#pragma unroll
    for (int kc = 0; kc < 2; ++kc) {
      bf16x8 bp0 = *(const bf16x8*)((const char*)lp0 + li * 128 +
                                    ((kc * 64 + lg * 16) ^ ((li & 7) << 4)));
      bf16x8 bp1 = *(const bf16x8*)((const char*)lp1 + li * 128 +
                                    ((kc * 64 + lg * 16) ^ ((li & 7) << 4)));
#pragma unroll
      for (int f = 0; f < 8; ++f) {
        bf16x8 av = *(const bf16x8*)(lv + (f * 16 + li) * 128 +
                                     ((kc * 64 + lg * 16) ^ ((li & 7) << 4)));
        acc_o[0][f] = __builtin_amdgcn_mfma_f32_16x16x32_bf16(av, bp0, acc_o[0][f], 0, 0, 0);
        acc_o[1][f] = __builtin_amdgcn_mfma_f32_16x16x32_bf16(av, bp1, acc_o[1][f], 0, 0, 0);
      }
    }

    if (it < 31) { wcur[0] = wn[0]; wcur[1] = wn[1]; }
    __syncthreads();  // next buffer staged+visible; this buffer free to overwrite
  }

  // epilogue: O[q][hd], hd = f*16 + lg*4 + r; 8B packed stores
#pragma unroll
  for (int g = 0; g < 2; ++g) {
    const float inv_l = 1.0f / l[g];
    ushort* xrow = X + (size_t)(b * 2048 + qbase + g * 16 + li) * 2048 + h * 128;
#pragma unroll
    for (int f = 0; f < 8; ++f) {
      union { ushort u[4]; uint2 v; } o;
#pragma unroll
      for (int r = 0; r < 4; ++r) o.u[r] = f2bf(acc_o[g][f][r] * inv_l);
      *(uint2*)(xrow + f * 16 + lg * 4) = o.v;
    }
  }
}

// ---------- launch ----------

extern "C" void kernel_launch(void* const* d_in, const int* in_sizes, int n_in,
                              void* d_out, int out_size, void* d_ws, size_t ws_size,
                              hipStream_t stream) {
  const float* inputs_q  = (const float*)d_in[0];
  const float* inputs_kv = (const float*)d_in[1];
  const int*   mask      = (const int*)d_in[2];
  const float* Wq        = (const float*)d_in[3];
  const float* Wk        = (const float*)d_in[4];
  const float* Wv        = (const float*)d_in[5];
  const float* Wo        = (const float*)d_in[6];
  float* out = (float*)d_out;
  char* ws = (char*)d_ws;

  uint*   maskp = (uint*)(ws + 0);                 //   2,097,152
  ushort* xq    = (ushort*)(ws + 2097152);         //  33,554,432 (reused as VT)
  ushort* xkv   = (ushort*)(ws + 35651584);        //  33,554,432 (reused as X)
  ushort* WqT   = (ushort*)(ws + 69206016);        //   8,388,608
  ushort* WkT   = (ushort*)(ws + 77594624);
  ushort* WvT   = (ushort*)(ws + 85983232);
  ushort* WoT   = (ushort*)(ws + 94371840);
  ushort* Qb    = (ushort*)(ws + 102760448);       //  33,554,432
  ushort* Kb    = (ushort*)(ws + 136314880);
  ushort* Vb    = (ushort*)(ws + 169869312);
  ushort* VTb   = xq;   // V^T, written after xq dead
  ushort* Xb    = xkv;  // attention output, written after xkv dead

  const long NE = 8192L * 2048;
  conv_bf16<<<8192, 256, 0, stream>>>(inputs_q,  xq,  NE);
  conv_bf16<<<8192, 256, 0, stream>>>(inputs_kv, xkv, NE);

  dim3 tb(32, 8);
  transpose_to_bf16<float><<<dim3(64, 64, 1), tb, 0, stream>>>(Wq, WqT, 2048, 2048);
  transpose_to_bf16<float><<<dim3(64, 64, 1), tb, 0, stream>>>(Wk, WkT, 2048, 2048);
  transpose_to_bf16<float><<<dim3(64, 64, 1), tb, 0, stream>>>(Wv, WvT, 2048, 2048);
  transpose_to_bf16<float><<<dim3(64, 64, 1), tb, 0, stream>>>(Wo, WoT, 2048, 2048);

  pack_mask<<<2048, 256, 0, stream>>>(mask, maskp);

  const float qscale = 0.08838834764831845f;  // 1/sqrt(128)
  gemm_bt<1><<<dim3(16, 64), 256, 0, stream>>>(xq,  WqT, Qb, 8192, 2048, 2048, qscale);
  gemm_bt<1><<<dim3(16, 64), 256, 0, stream>>>(xkv, WkT, Kb, 8192, 2048, 2048, 1.0f);
  gemm_bt<1><<<dim3(16, 64), 256, 0, stream>>>(xkv, WvT, Vb, 8192, 2048, 2048, 1.0f);

  transpose_to_bf16<ushort><<<dim3(64, 64, 4), tb, 0, stream>>>(Vb, VTb, 2048, 2048);

  flash_attn4<<<1024, 256, 0, stream>>>(Qb, Kb, VTb, maskp, Xb);

  gemm_bt<0><<<dim3(16, 64), 256, 0, stream>>>(Xb, WoT, out, 8192, 2048, 2048, 1.0f);
}

// Round 5
// 600.990 us; speedup vs baseline: 1.2842x; 1.1294x over previous
//
#include <hip/hip_runtime.h>

typedef __attribute__((ext_vector_type(4))) float f32x4;
typedef __attribute__((ext_vector_type(8))) short bf16x8;
typedef unsigned int uint;
typedef unsigned short ushort;

// ---------- helpers ----------

__device__ __forceinline__ ushort f2bf(float f) {
  union { float f; uint u; } v; v.f = f;
  uint u = v.u;
  uint r = (u + 0x7FFFu + ((u >> 16) & 1u)) >> 16;  // RNE
  return (ushort)r;
}
__device__ __forceinline__ float to_f32(float f) { return f; }
__device__ __forceinline__ float to_f32(ushort u) {
  union { uint u; float f; } v; v.u = ((uint)u) << 16;
  return v.f;
}

// packed f32x2 -> bf16x2 (RNE), 1 instruction
__device__ __forceinline__ uint cvt_pk_bf16(float lo, float hi) {
  uint r;
  asm("v_cvt_pk_bf16_f32 %0, %1, %2" : "=v"(r) : "v"(lo), "v"(hi));
  return r;
}

__device__ __forceinline__ void gload_lds16(const void* g, void* l) {
  __builtin_amdgcn_global_load_lds(
      (const __attribute__((address_space(1))) void*)g,
      (__attribute__((address_space(3))) void*)l, 16, 0, 0);
}

// ---------- pre-pass kernels ----------

__global__ __launch_bounds__(256)
void conv_bf16(const float* __restrict__ in, ushort* __restrict__ out, long n) {
  long i = ((long)blockIdx.x * 256 + threadIdx.x) * 8;
  if (i >= n) return;
  float4 a = *(const float4*)(in + i);
  float4 b = *(const float4*)(in + i + 4);
  union { ushort u[8]; uint4 v; } o;
  o.u[0] = f2bf(a.x); o.u[1] = f2bf(a.y); o.u[2] = f2bf(a.z); o.u[3] = f2bf(a.w);
  o.u[4] = f2bf(b.x); o.u[5] = f2bf(b.y); o.u[6] = f2bf(b.z); o.u[7] = f2bf(b.w);
  *(uint4*)(out + i) = o.v;
}

template<typename T>
__global__ __launch_bounds__(256)
void transpose_to_bf16(const T* __restrict__ in, ushort* __restrict__ out, int R, int C) {
  __shared__ float tile[32][33];
  const size_t boff = (size_t)blockIdx.z * R * C;
  in += boff; out += boff;
  const int r0 = blockIdx.y * 32, c0 = blockIdx.x * 32;
  const int x = threadIdx.x, y = threadIdx.y;
#pragma unroll
  for (int j = 0; j < 32; j += 8)
    tile[y + j][x] = to_f32(in[(size_t)(r0 + y + j) * C + c0 + x]);
  __syncthreads();
#pragma unroll
  for (int j = 0; j < 32; j += 8)
    out[(size_t)(c0 + y + j) * R + r0 + x] = f2bf(tile[x][y + j]);
}

__global__ __launch_bounds__(256)
void pack_mask(const int* __restrict__ in, uint* __restrict__ out) {
  long t = (long)blockIdx.x * 256 + threadIdx.x;
  const int4* p = (const int4*)(in + t * 32);
  uint w = 0;
#pragma unroll
  for (int i = 0; i < 8; ++i) {
    int4 v = p[i];
    w |= (v.x > 0 ? 1u : 0u) << (i * 4 + 0);
    w |= (v.y > 0 ? 1u : 0u) << (i * 4 + 1);
    w |= (v.z > 0 ? 1u : 0u) << (i * 4 + 2);
    w |= (v.w > 0 ? 1u : 0u) << (i * 4 + 3);
  }
  out[t] = w;
}

// ---------- GEMM v2: 256x256 tile, counted-vmcnt pipeline ----------
// C[M][N] = A[M][K] * Bt[N][K]^T. 512 threads = 8 waves (2M x 4N), wave tile
// 128x64, acc 8x4 f32x4. LDS 2x(32KB A + 32KB B) = 128 KB double buffer.
// Per K-tile: raw_barrier; issue 8 gload_lds for tile t+1 into freed buffer;
// s_waitcnt vmcnt(8) (tile t retired, t+1 stays IN FLIGHT across the barrier);
// raw_barrier; compute 64 MFMA in 4 quadrant-phases (A-frags reg-cached per
// m-half). Row-XOR swizzle (row&7)<<4 on 128-B rows: pre-swizzled global
// source + swizzled ds_read (both-sides rule). grid = (N/256, M/256); natural
// dispatch puts n-panel = blockIdx.x on XCD x -> B-panel (1 MB) L2-resident.

template<int OUT_BF16>
__global__ __launch_bounds__(512, 2)
void gemm256(const ushort* __restrict__ A, const ushort* __restrict__ Bt,
             void* __restrict__ C, int M, int N, int K, float scale) {
  __shared__ ushort lA[2][256 * 64];
  __shared__ ushort lB[2][256 * 64];
  const int tid = threadIdx.x;
  const int wid = tid >> 6, lane = tid & 63;
  const int lg = lane >> 4, li = lane & 15;
  const int wm = wid >> 2, wn = wid & 3;
  const int m0 = blockIdx.y * 256, n0 = blockIdx.x * 256;

  // per-thread staging byte offsets; LDS linear off = i*8192 + tid*16
  int offA[4], offB[4];
#pragma unroll
  for (int i = 0; i < 4; ++i) {
    int off = i * 8192 + tid * 16;
    int row = off >> 7;                         // 128 B per row (64 bf16)
    int col = (off & 127) ^ ((row & 7) << 4);   // inverse-swizzled source col
    offA[i] = (m0 + row) * (K * 2) + col;
    offB[i] = (n0 + row) * (K * 2) + col;
  }
  const char* Ab = (const char*)A;
  const char* Bb = (const char*)Bt;

#define STAGE256(bufi, ktb)                                                   \
  do {                                                                        \
    _Pragma("unroll") for (int i = 0; i < 4; ++i)                             \
      gload_lds16(Ab + (size_t)(offA[i] + (ktb)),                             \
                  (char*)lA[bufi] + i * 8192 + wid * 1024);                   \
    _Pragma("unroll") for (int i = 0; i < 4; ++i)                             \
      gload_lds16(Bb + (size_t)(offB[i] + (ktb)),                             \
                  (char*)lB[bufi] + i * 8192 + wid * 1024);                   \
  } while (0)

  f32x4 acc[8][4] = {};
  const int NT = K >> 6;

  STAGE256(0, 0);  // tile 0

  for (int t = 0; t < NT; ++t) {
    const int cur = t & 1;
    if (t > 0) __builtin_amdgcn_s_barrier();  // all waves done reading buf cur^1
    if (t + 1 < NT) {
      STAGE256(cur ^ 1, (t + 1) * 128);       // tile t+1 -> freed buffer
      asm volatile("s_waitcnt vmcnt(8)" ::: "memory");  // tile t retired only
    } else {
      asm volatile("s_waitcnt vmcnt(0)" ::: "memory");
    }
    __builtin_amdgcn_s_barrier();             // tile t visible to all waves
    __builtin_amdgcn_sched_barrier(0);

    const char* la = (const char*)lA[cur];
    const char* lb = (const char*)lB[cur];
    bf16x8 afr[4][2];
#pragma unroll
    for (int q = 0; q < 4; ++q) {
      const int mh = q >> 1;
      const int nh = (q == 1 || q == 2) ? 1 : 0;  // order (0,0)(0,1)(1,1)(1,0)
      if ((q & 1) == 0) {  // (re)load A-frags for this m-half, reuse next phase
#pragma unroll
        for (int mi = 0; mi < 4; ++mi)
#pragma unroll
          for (int ks = 0; ks < 2; ++ks) {
            const int row = wm * 128 + (mh * 4 + mi) * 16 + li;
            afr[mi][ks] = *(const bf16x8*)(
                la + row * 128 + ((ks * 64 + lg * 16) ^ ((li & 7) << 4)));
          }
      }
      bf16x8 bfr[2][2];
#pragma unroll
      for (int ni = 0; ni < 2; ++ni)
#pragma unroll
        for (int ks = 0; ks < 2; ++ks) {
          const int row = wn * 64 + (nh * 2 + ni) * 16 + li;
          bfr[ni][ks] = *(const bf16x8*)(
              lb + row * 128 + ((ks * 64 + lg * 16) ^ ((li & 7) << 4)));
        }
      __builtin_amdgcn_s_setprio(1);
#pragma unroll
      for (int ks = 0; ks < 2; ++ks)
#pragma unroll
        for (int mi = 0; mi < 4; ++mi)
#pragma unroll
          for (int ni = 0; ni < 2; ++ni)
            acc[mh * 4 + mi][nh * 2 + ni] = __builtin_amdgcn_mfma_f32_16x16x32_bf16(
                afr[mi][ks], bfr[ni][ks], acc[mh * 4 + mi][nh * 2 + ni], 0, 0, 0);
      __builtin_amdgcn_s_setprio(0);
    }
  }
#undef STAGE256

  // epilogue: C/D layout row = lg*4 + r, col = li
  const int r0 = m0 + wm * 128 + lg * 4;
  const int c0 = n0 + wn * 64 + li;
#pragma unroll
  for (int mi = 0; mi < 8; ++mi)
#pragma unroll
    for (int ni = 0; ni < 4; ++ni)
#pragma unroll
      for (int r = 0; r < 4; ++r) {
        size_t idx = (size_t)(r0 + mi * 16 + r) * N + (c0 + ni * 16);
        float v = acc[mi][ni][r] * scale;
        if (OUT_BF16) ((ushort*)C)[idx] = f2bf(v);
        else          ((float*)C)[idx]  = v;
      }
}

// ---------- flash attention v4 (unchanged from round 4) ----------

__global__ __launch_bounds__(256, 2)
void flash_attn4(const ushort* __restrict__ Q, const ushort* __restrict__ K,
                 const ushort* __restrict__ VT, const uint* __restrict__ maskp,
                 ushort* __restrict__ X) {
  __shared__ ushort lK[2][64 * 128];    // [kv][hd], 256-B rows, swz (row&15)<<4
  __shared__ ushort lVT[2][128 * 64];   // [hd][kv], 128-B rows, swz (row&7)<<4
  __shared__ ushort lP[4][2][16 * 64];  // per-wave, per-group P^T [q][k]

  const int tid = threadIdx.x;
  const int wid = tid >> 6;
  const int lane = tid & 63;
  const int lg = lane >> 4, li = lane & 15;

  const int flat = blockIdx.x;
  const int xcd = flat & 7;
  const int j = flat >> 3;            // 0..127
  const int bh = xcd * 8 + (j >> 4);
  const int qt = j & 15;
  const int b = bh >> 4, h = bh & 15;
  const int q0 = qt * 128;
  const int qbase = q0 + wid * 32;    // wave's 32 q-rows

  bf16x8 bq[2][4];
#pragma unroll
  for (int g = 0; g < 2; ++g) {
    const ushort* qrow = Q + (size_t)(b * 2048 + qbase + g * 16 + li) * 2048 + h * 128;
#pragma unroll
    for (int kk = 0; kk < 4; ++kk)
      bq[g][kk] = *(const bf16x8*)(qrow + kk * 32 + lg * 8);
  }

  const uint* mqb[2] = {
      maskp + (size_t)(b * 2048 + qbase + li) * 64,
      maskp + (size_t)(b * 2048 + qbase + 16 + li) * 64};
  uint2 wcur[2] = {*(const uint2*)mqb[0], *(const uint2*)mqb[1]};

  f32x4 acc_o[2][8] = {};
  float m[2] = {-3e38f, -3e38f}, l[2] = {0.f, 0.f};

  const char* gk[4];
  const char* gv[4];
#pragma unroll
  for (int i = 0; i < 4; ++i) {
    int fl = i * 4096 + tid * 16;
    int rowK = fl >> 8;
    int colK = (fl & 255) ^ ((rowK & 15) << 4);
    gk[i] = (const char*)K + ((size_t)(b * 2048 + rowK) * 2048 + h * 128) * 2 + colK;
    int rowV = fl >> 7;
    int colV = (fl & 127) ^ ((rowV & 7) << 4);
    gv[i] = (const char*)VT + ((size_t)((b * 16 + h) * 128 + rowV) * 2048) * 2 + colV;
  }

#pragma unroll
  for (int i = 0; i < 4; ++i)
    gload_lds16(gk[i], (char*)lK[0] + i * 4096 + wid * 1024);
#pragma unroll
  for (int i = 0; i < 4; ++i)
    gload_lds16(gv[i], (char*)lVT[0] + i * 4096 + wid * 1024);
#pragma unroll
  for (int i = 0; i < 4; ++i) { gk[i] += 262144; gv[i] += 128; }
  __syncthreads();

  ushort* lp0 = lP[wid][0];
  ushort* lp1 = lP[wid][1];

  for (int it = 0; it < 32; ++it) {
    const int cur = it & 1;
    uint2 wn[2];
    if (it < 31) {
#pragma unroll
      for (int i = 0; i < 4; ++i)
        gload_lds16(gk[i], (char*)lK[cur ^ 1] + i * 4096 + wid * 1024);
#pragma unroll
      for (int i = 0; i < 4; ++i)
        gload_lds16(gv[i], (char*)lVT[cur ^ 1] + i * 4096 + wid * 1024);
#pragma unroll
      for (int i = 0; i < 4; ++i) { gk[i] += 262144; gv[i] += 128; }
      wn[0] = *(const uint2*)(mqb[0] + (it + 1) * 2);
      wn[1] = *(const uint2*)(mqb[1] + (it + 1) * 2);
    }
    const char* lk = (const char*)lK[cur];
    const char* lv = (const char*)lVT[cur];

    f32x4 accs[2][4] = {};
#pragma unroll
    for (int kk = 0; kk < 4; ++kk)
#pragma unroll
      for (int n = 0; n < 4; ++n) {
        bf16x8 ak = *(const bf16x8*)(lk + (n * 16 + li) * 256 +
                                     ((kk * 64 + lg * 16) ^ (li << 4)));
        accs[0][n] = __builtin_amdgcn_mfma_f32_16x16x32_bf16(ak, bq[0][kk], accs[0][n], 0, 0, 0);
        accs[1][n] = __builtin_amdgcn_mfma_f32_16x16x32_bf16(ak, bq[1][kk], accs[1][n], 0, 0, 0);
      }

#pragma unroll
    for (int g = 0; g < 2; ++g) {
      float sv[16];
      float pmax = -3e38f;
#pragma unroll
      for (int n = 0; n < 4; ++n) {
        uint w = (n < 2) ? wcur[g].x : wcur[g].y;
#pragma unroll
        for (int r = 0; r < 4; ++r) {
          int bit = (n & 1) * 16 + lg * 4 + r;
          float s = ((w >> bit) & 1u) ? accs[g][n][r] : -1e10f;
          sv[n * 4 + r] = s;
          pmax = fmaxf(pmax, s);
        }
      }
      pmax = fmaxf(pmax, __shfl_xor(pmax, 16, 64));
      pmax = fmaxf(pmax, __shfl_xor(pmax, 32, 64));

      if (!__all(pmax - m[g] <= 8.0f)) {
        float mnew = fmaxf(m[g], pmax);
        float alpha = __expf(m[g] - mnew);
        l[g] *= alpha;
#pragma unroll
        for (int f = 0; f < 8; ++f)
#pragma unroll
          for (int r = 0; r < 4; ++r) acc_o[g][f][r] *= alpha;
        m[g] = mnew;
      }

      float sum = 0.f;
      uint pk[8];
#pragma unroll
      for (int i = 0; i < 8; ++i) {
        float p0 = __expf(sv[2 * i] - m[g]);
        float p1 = __expf(sv[2 * i + 1] - m[g]);
        sum += p0 + p1;
        pk[i] = cvt_pk_bf16(p0, p1);
      }
      sum += __shfl_xor(sum, 16, 64);
      sum += __shfl_xor(sum, 32, 64);
      l[g] += sum;

      ushort* lpg = g ? lp1 : lp0;
#pragma unroll
      for (int n = 0; n < 4; ++n) {
        uint2 pw; pw.x = pk[2 * n]; pw.y = pk[2 * n + 1];
        *(uint2*)((char*)lpg + li * 128 + ((n * 32 + lg * 8) ^ ((li & 7) << 4))) = pw;
      }
    }

#pragma unroll
    for (int kc = 0; kc < 2; ++kc) {
      bf16x8 bp0 = *(const bf16x8*)((const char*)lp0 + li * 128 +
                                    ((kc * 64 + lg * 16) ^ ((li & 7) << 4)));
      bf16x8 bp1 = *(const bf16x8*)((const char*)lp1 + li * 128 +
                                    ((kc * 64 + lg * 16) ^ ((li & 7) << 4)));
#pragma unroll
      for (int f = 0; f < 8; ++f) {
        bf16x8 av = *(const bf16x8*)(lv + (f * 16 + li) * 128 +
                                     ((kc * 64 + lg * 16) ^ ((li & 7) << 4)));
        acc_o[0][f] = __builtin_amdgcn_mfma_f32_16x16x32_bf16(av, bp0, acc_o[0][f], 0, 0, 0);
        acc_o[1][f] = __builtin_amdgcn_mfma_f32_16x16x32_bf16(av, bp1, acc_o[1][f], 0, 0, 0);
      }
    }

    if (it < 31) { wcur[0] = wn[0]; wcur[1] = wn[1]; }
    __syncthreads();
  }

#pragma unroll
  for (int g = 0; g < 2; ++g) {
    const float inv_l = 1.0f / l[g];
    ushort* xrow = X + (size_t)(b * 2048 + qbase + g * 16 + li) * 2048 + h * 128;
#pragma unroll
    for (int f = 0; f < 8; ++f) {
      union { ushort u[4]; uint2 v; } o;
#pragma unroll
      for (int r = 0; r < 4; ++r) o.u[r] = f2bf(acc_o[g][f][r] * inv_l);
      *(uint2*)(xrow + f * 16 + lg * 4) = o.v;
    }
  }
}

// ---------- launch ----------

extern "C" void kernel_launch(void* const* d_in, const int* in_sizes, int n_in,
                              void* d_out, int out_size, void* d_ws, size_t ws_size,
                              hipStream_t stream) {
  const float* inputs_q  = (const float*)d_in[0];
  const float* inputs_kv = (const float*)d_in[1];
  const int*   mask      = (const int*)d_in[2];
  const float* Wq        = (const float*)d_in[3];
  const float* Wk        = (const float*)d_in[4];
  const float* Wv        = (const float*)d_in[5];
  const float* Wo        = (const float*)d_in[6];
  float* out = (float*)d_out;
  char* ws = (char*)d_ws;

  uint*   maskp = (uint*)(ws + 0);                 //   2,097,152
  ushort* xq    = (ushort*)(ws + 2097152);         //  33,554,432 (reused as VT)
  ushort* xkv   = (ushort*)(ws + 35651584);        //  33,554,432 (reused as X)
  ushort* WqT   = (ushort*)(ws + 69206016);        //   8,388,608
  ushort* WkT   = (ushort*)(ws + 77594624);
  ushort* WvT   = (ushort*)(ws + 85983232);
  ushort* WoT   = (ushort*)(ws + 94371840);
  ushort* Qb    = (ushort*)(ws + 102760448);       //  33,554,432
  ushort* Kb    = (ushort*)(ws + 136314880);
  ushort* Vb    = (ushort*)(ws + 169869312);
  ushort* VTb   = xq;   // V^T, written after xq dead
  ushort* Xb    = xkv;  // attention output, written after xkv dead

  const long NE = 8192L * 2048;
  conv_bf16<<<8192, 256, 0, stream>>>(inputs_q,  xq,  NE);
  conv_bf16<<<8192, 256, 0, stream>>>(inputs_kv, xkv, NE);

  dim3 tb(32, 8);
  transpose_to_bf16<float><<<dim3(64, 64, 1), tb, 0, stream>>>(Wq, WqT, 2048, 2048);
  transpose_to_bf16<float><<<dim3(64, 64, 1), tb, 0, stream>>>(Wk, WkT, 2048, 2048);
  transpose_to_bf16<float><<<dim3(64, 64, 1), tb, 0, stream>>>(Wv, WvT, 2048, 2048);
  transpose_to_bf16<float><<<dim3(64, 64, 1), tb, 0, stream>>>(Wo, WoT, 2048, 2048);

  pack_mask<<<2048, 256, 0, stream>>>(mask, maskp);

  const float qscale = 0.08838834764831845f;  // 1/sqrt(128)
  gemm256<1><<<dim3(8, 32), 512, 0, stream>>>(xq,  WqT, Qb, 8192, 2048, 2048, qscale);
  gemm256<1><<<dim3(8, 32), 512, 0, stream>>>(xkv, WkT, Kb, 8192, 2048, 2048, 1.0f);
  gemm256<1><<<dim3(8, 32), 512, 0, stream>>>(xkv, WvT, Vb, 8192, 2048, 2048, 1.0f);

  transpose_to_bf16<ushort><<<dim3(64, 64, 4), tb, 0, stream>>>(Vb, VTb, 2048, 2048);

  flash_attn4<<<1024, 256, 0, stream>>>(Qb, Kb, VTb, maskp, Xb);

  gemm256<0><<<dim3(8, 32), 512, 0, stream>>>(Xb, WoT, out, 8192, 2048, 2048, 1.0f);
}